// Round 11
// baseline (412.706 us; speedup 1.0000x reference)
//
#include <hip/hip_runtime.h>
#include <hip/hip_bf16.h>

#define T_DIM 4096
#define B_DIM 32
#define I_DIM 512
#define O_DIM 512
#define M_DIM (T_DIM * B_DIM)   // 131072
#define PARAM 0.1f
#define ISCALE 1.1111112f       // 1/(1-p)

#define STRIP 32
#define TAPS 8                  // p^8 = 1e-8 << bf16 eps

typedef __attribute__((ext_vector_type(8))) short bf16x8;
typedef __attribute__((ext_vector_type(4))) float f32x4;

__device__ __forceinline__ unsigned short f2bf(float f) {
    union { __hip_bfloat16 b; unsigned short u; } cv;
    cv.b = __float2bfloat16(f);
    return cv.u;
}

// --- W fp32 -> bf16 (0.5 MB, ws offset 0) ---
__global__ __launch_bounds__(256) void wcvt_kernel(const float* __restrict__ W,
                                                   unsigned short* __restrict__ Wb) {
    const int i = (blockIdx.x * 256 + threadIdx.x) * 4;
    f32x4 v = *(const f32x4*)(W + i);
    ushort4 o;
    o.x = f2bf(v[0]); o.y = f2bf(v[1]); o.z = f2bf(v[2]); o.w = f2bf(v[3]);
    *(ushort4*)(Wb + i) = o;
}

// --- EMA over raw X (linearity: EMA(XW+b) = EMA(X)W + s[t]*b). Strip-parallel,
// TAPS warm-up reads raw X; bf16 output compacted into d_ws. ---
__global__ __launch_bounds__(256) void xema_kernel(const float* __restrict__ X,
                                                   unsigned short* __restrict__ Xv) {
    const int s   = blockIdx.x >> 4;                 // strip 0..127
    const int blk = blockIdx.x & 15;
    const int col = (blk * 256 + threadIdx.x) * 4;
    const int t0  = s * STRIP;
    const int b   = col >> 9;
    const int o   = col & 511;

    const float* xin = X + (size_t)t0 * 16384 + col;
    unsigned short* xout = Xv + (size_t)(t0 * 32 + b) * 512 + o;

    f32x4 v = {0.f, 0.f, 0.f, 0.f};
    if (s > 0) {
        const float* w = xin - (size_t)TAPS * 16384;
        #pragma unroll
        for (int j = 0; j < TAPS; ++j)
            v = PARAM * v + *(const f32x4*)(w + (size_t)j * 16384);
    }

    f32x4 bufA[4], bufB[4];
    #pragma unroll
    for (int j = 0; j < 4; ++j) bufA[j] = *(const f32x4*)(xin + (size_t)j * 16384);

    #pragma unroll
    for (int i = 0; i < STRIP; i += 8) {
        #pragma unroll
        for (int j = 0; j < 4; ++j)
            bufB[j] = *(const f32x4*)(xin + (size_t)(i + 4 + j) * 16384);
        #pragma unroll
        for (int j = 0; j < 4; ++j) {
            v = PARAM * v + bufA[j];
            ushort4 pk; pk.x = f2bf(v[0]); pk.y = f2bf(v[1]); pk.z = f2bf(v[2]); pk.w = f2bf(v[3]);
            *(ushort4*)(xout + (size_t)(i + j) * 16384) = pk;
        }
        if (i + 8 < STRIP) {
            #pragma unroll
            for (int j = 0; j < 4; ++j)
                bufA[j] = *(const f32x4*)(xin + (size_t)(i + 8 + j) * 16384);
        }
        #pragma unroll
        for (int j = 0; j < 4; ++j) {
            v = PARAM * v + bufB[j];
            ushort4 pk; pk.x = f2bf(v[0]); pk.y = f2bf(v[1]); pk.z = f2bf(v[2]); pk.w = f2bf(v[3]);
            *(ushort4*)(xout + (size_t)(i + 4 + j) * 16384) = pk;
        }
    }
}

// --- GEMM: register-direct, ZERO LDS, ZERO barriers. Each wave owns a 128x64
// output tile (acc 8x4); its MFMA fragments are contiguous 16B global loads
// (row = lane&15, k-half = lane>>4), so A/B load straight into frag registers.
// Full K unroll (8 steps, kk-split) -> compiler software-pipelines freely; no
// convoy, no vmcnt(0) drains. Block = 4 n-waves sharing a 128-row A panel
// (L1/L2 hits); XCD-chunked bids keep A panels and the 512KB W L2-hot. ---
__global__ __launch_bounds__(256, 2) void gemm_kernel(const unsigned short* __restrict__ Xv,
                                                      const unsigned short* __restrict__ Wb,
                                                      const float* __restrict__ bias,
                                                      float* __restrict__ Y) {
    const int tid  = threadIdx.x;
    const int lane = tid & 63;
    const int wave = tid >> 6;        // 0..3 = n-quarter within the 256-col half

    // 2048 blocks: xcd = bid&7; per XCD, bn toggles fastest then m advances ->
    // the col-half pair of one m-group is temporally adjacent on one XCD.
    const int bid  = blockIdx.x;
    const int swz  = (bid & 7) * 256 + (bid >> 3);
    const int bn   = swz & 1;                     // 256-col half
    const int mg   = swz >> 1;                    // 0..1023, 128-row group
    const int row0 = mg * 128;
    const int col0 = bn * 256 + wave * 64;

    // Fragment bases: one contiguous 16B load per (mf/nf, ks, kk).
    const unsigned short* aBase = Xv + (size_t)(row0 + (lane & 15)) * 512 + ((lane >> 4) << 3);
    const unsigned short* bBase = Wb + (size_t)(col0 + (lane & 15)) * 512 + ((lane >> 4) << 3);

    f32x4 acc[8][4] = {};

    #pragma unroll
    for (int ks = 0; ks < 8; ++ks) {
        bf16x8 a0[8], a1[8], b0[4], b1[4];
        #pragma unroll
        for (int nf = 0; nf < 4; ++nf) {
            b0[nf] = *(const bf16x8*)(bBase + (size_t)nf * 16 * 512 + ks * 64);
            b1[nf] = *(const bf16x8*)(bBase + (size_t)nf * 16 * 512 + ks * 64 + 32);
        }
        #pragma unroll
        for (int mf = 0; mf < 8; ++mf) {
            a0[mf] = *(const bf16x8*)(aBase + (size_t)mf * 16 * 512 + ks * 64);
            a1[mf] = *(const bf16x8*)(aBase + (size_t)mf * 16 * 512 + ks * 64 + 32);
        }
        #pragma unroll
        for (int mf = 0; mf < 8; ++mf)
            #pragma unroll
            for (int nf = 0; nf < 4; ++nf)
                acc[mf][nf] = __builtin_amdgcn_mfma_f32_16x16x32_bf16(
                    a0[mf], b0[nf], acc[mf][nf], 0, 0, 0);
        #pragma unroll
        for (int mf = 0; mf < 8; ++mf)
            #pragma unroll
            for (int nf = 0; nf < 4; ++nf)
                acc[mf][nf] = __builtin_amdgcn_mfma_f32_16x16x32_bf16(
                    a1[mf], b1[nf], acc[mf][nf], 0, 0, 0);
    }

    // bias EMA-scale s[t] = (1 - p^(t+1))/(1-p); t index = row>>5; within the
    // 128-row wave tile, t offset = mf>>1.
    float sc4[4];
    #pragma unroll
    for (int tt = 0; tt < 4; ++tt) {
        const int t_ = (row0 >> 5) + tt;
        sc4[tt] = (1.0f - __expf(-2.3025851f * (float)(t_ + 1))) * ISCALE;
    }
    float bv[4];
    #pragma unroll
    for (int nf = 0; nf < 4; ++nf)
        bv[nf] = bias[col0 + nf * 16 + (lane & 15)];

    #pragma unroll
    for (int mf = 0; mf < 8; ++mf) {
        #pragma unroll
        for (int nf = 0; nf < 4; ++nf) {
            const int gcol = col0 + nf * 16 + (lane & 15);
            #pragma unroll
            for (int j = 0; j < 4; ++j) {
                const int grow = row0 + mf * 16 + ((lane >> 4) << 2) + j;
                Y[(size_t)grow * O_DIM + gcol] = acc[mf][nf][j] + sc4[mf >> 1] * bv[nf];
            }
        }
    }
}

extern "C" void kernel_launch(void* const* d_in, const int* in_sizes, int n_in,
                              void* d_out, int out_size, void* d_ws, size_t ws_size,
                              hipStream_t stream) {
    const float* X    = (const float*)d_in[0];
    const float* W    = (const float*)d_in[1];
    const float* bias = (const float*)d_in[2];
    float* Y = (float*)d_out;
    unsigned short* Wb = (unsigned short*)d_ws;                       // 512 KB
    unsigned short* Xv = (unsigned short*)((char*)d_ws + (1 << 20));  // 134 MB

    wcvt_kernel<<<dim3(O_DIM * I_DIM / (256 * 4)), dim3(256), 0, stream>>>(W, Wb);
    xema_kernel<<<dim3((T_DIM / STRIP) * 16), dim3(256), 0, stream>>>(X, Xv);
    gemm_kernel<<<dim3((M_DIM / 128) * 2), dim3(256), 0, stream>>>(Xv, Wb, bias, Y);
}